// Round 3
// baseline (130.862 us; speedup 1.0000x reference)
//
#include <hip/hip_runtime.h>

#define HORIZON 10
#define NUM_REGIONS 64
#define BB 32
#define TT 12
#define NN 100000

typedef float  f32x4 __attribute__((ext_vector_type(4)));
typedef int    i32x4 __attribute__((ext_vector_type(4)));

// Kernel A: per (b, 4-node group) — time-mean of feature 0, write 10 horizon
// copies (float4 nontemporal), accumulate per-region sums via LDS -> global.
__global__ __launch_bounds__(256) void mean_kernel(
    const float* __restrict__ x, const int* __restrict__ cid,
    float* __restrict__ out0, float* __restrict__ gsum)
{
    __shared__ float lsum[NUM_REGIONS];
    const int tid = threadIdx.x;
    if (tid < NUM_REGIONS) lsum[tid] = 0.0f;
    __syncthreads();

    const int b = blockIdx.y;
    const int i = blockIdx.x * blockDim.x + tid;   // group index: nodes 4i..4i+3
    const int n0 = 4 * i;
    if (n0 < NN) {
        float s0 = 0.0f, s1 = 0.0f, s2 = 0.0f, s3 = 0.0f;
        #pragma unroll
        for (int t = 0; t < TT; ++t) {
            const f32x4* p = reinterpret_cast<const f32x4*>(
                x + ((size_t)(b * TT + t) * NN + n0) * 2);
            const f32x4 v0 = __builtin_nontemporal_load(p);       // n0,n0+1
            const f32x4 v1 = __builtin_nontemporal_load(p + 1);   // n0+2,n0+3
            s0 += v0.x;  s1 += v0.z;
            s2 += v1.x;  s3 += v1.z;
        }
        f32x4 mv;
        mv.x = s0 * (1.0f / 12.0f);
        mv.y = s1 * (1.0f / 12.0f);
        mv.z = s2 * (1.0f / 12.0f);
        mv.w = s3 * (1.0f / 12.0f);
        const size_t obase = (size_t)b * HORIZON * NN + n0;
        #pragma unroll
        for (int h = 0; h < HORIZON; ++h) {
            __builtin_nontemporal_store(
                mv, reinterpret_cast<f32x4*>(out0 + obase + (size_t)h * NN));
        }
        const i32x4 c = *reinterpret_cast<const i32x4*>(cid + n0);
        atomicAdd(&lsum[c.x], mv.x);
        atomicAdd(&lsum[c.y], mv.y);
        atomicAdd(&lsum[c.z], mv.z);
        atomicAdd(&lsum[c.w], mv.w);
    }
    __syncthreads();
    if (tid < NUM_REGIONS) {
        atomicAdd(&gsum[b * NUM_REGIONS + tid], lsum[tid]);
    }
}

// Kernel B: region counts.
__global__ __launch_bounds__(256) void count_kernel(
    const int* __restrict__ cid, float* __restrict__ gcount)
{
    __shared__ float lc[NUM_REGIONS];
    const int tid = threadIdx.x;
    if (tid < NUM_REGIONS) lc[tid] = 0.0f;
    __syncthreads();
    const int n = blockIdx.x * blockDim.x + tid;
    if (n < NN) atomicAdd(&lc[cid[n]], 1.0f);
    __syncthreads();
    if (tid < NUM_REGIONS) atomicAdd(&gcount[tid], lc[tid]);
}

// Kernel C: regional means broadcast over horizon.
__global__ __launch_bounds__(256) void finalize_kernel(
    const float* __restrict__ gsum, const float* __restrict__ gcount,
    float* __restrict__ out1)
{
    const int idx = blockIdx.x * blockDim.x + threadIdx.x;  // 0 .. B*R-1
    if (idx >= BB * NUM_REGIONS) return;
    const int b = idx >> 6;
    const int r = idx & 63;
    const float v = gsum[idx] / gcount[r];
    const size_t base = (size_t)b * HORIZON * NUM_REGIONS + r;
    #pragma unroll
    for (int h = 0; h < HORIZON; ++h) {
        out1[base + (size_t)h * NUM_REGIONS] = v;
    }
}

extern "C" void kernel_launch(void* const* d_in, const int* in_sizes, int n_in,
                              void* d_out, int out_size, void* d_ws, size_t ws_size,
                              hipStream_t stream) {
    const float* x   = (const float*)d_in[0];
    const int*   cid = (const int*)d_in[1];
    float* out0 = (float*)d_out;
    float* out1 = out0 + (size_t)BB * HORIZON * NN;

    float* gsum   = (float*)d_ws;                 // BB*NUM_REGIONS floats
    float* gcount = gsum + BB * NUM_REGIONS;      // NUM_REGIONS floats

    (void)hipMemsetAsync(d_ws, 0,
                   (BB * NUM_REGIONS + NUM_REGIONS) * sizeof(float), stream);

    dim3 gridA((NN / 4 + 255) / 256, BB);
    mean_kernel<<<gridA, 256, 0, stream>>>(x, cid, out0, gsum);

    count_kernel<<<(NN + 255) / 256, 256, 0, stream>>>(cid, gcount);

    finalize_kernel<<<(BB * NUM_REGIONS + 255) / 256, 256, 0, stream>>>(
        gsum, gcount, out1);
}

// Round 4
// 125.284 us; speedup vs baseline: 1.0445x; 1.0445x over previous
//
#include <hip/hip_runtime.h>

#define HORIZON 10
#define NUM_REGIONS 64
#define BB 32
#define TT 12
#define NN 100000

typedef float f32x2 __attribute__((ext_vector_type(2)));
typedef float f32x4 __attribute__((ext_vector_type(4)));

// Phase 1: time-mean of feature 0 -> means[b][n] in workspace,
// plus per-region sums via LDS -> global atomics.
__global__ __launch_bounds__(256) void reduce_kernel(
    const float* __restrict__ x, const int* __restrict__ cid,
    float* __restrict__ means, float* __restrict__ gsum)
{
    __shared__ float lsum[NUM_REGIONS];
    const int tid = threadIdx.x;
    if (tid < NUM_REGIONS) lsum[tid] = 0.0f;
    __syncthreads();

    const int b = blockIdx.y;
    const int i = blockIdx.x * 256 + tid;   // pair index: nodes 2i, 2i+1
    const int n0 = 2 * i;
    if (n0 < NN) {
        float s0 = 0.0f, s1 = 0.0f;
        #pragma unroll
        for (int t = 0; t < TT; ++t) {
            const f32x4 v = *reinterpret_cast<const f32x4*>(
                x + ((size_t)(b * TT + t) * NN + n0) * 2);
            s0 += v.x;   // feature 0, node n0
            s1 += v.z;   // feature 0, node n0+1
        }
        const float m0 = s0 * (1.0f / 12.0f);
        const float m1 = s1 * (1.0f / 12.0f);
        f32x2 mv; mv.x = m0; mv.y = m1;
        *reinterpret_cast<f32x2*>(means + (size_t)b * NN + n0) = mv;
        atomicAdd(&lsum[cid[n0]], m0);
        atomicAdd(&lsum[cid[n0 + 1]], m1);
    }
    __syncthreads();
    if (tid < NUM_REGIONS) {
        atomicAdd(&gsum[b * NUM_REGIONS + tid], lsum[tid]);
    }
}

// Phase 2: broadcast means over horizon. One float4 per thread,
// perfectly sequential stores; means reads hit L2/L3 (12.8 MB).
__global__ __launch_bounds__(256) void broadcast_kernel(
    const float* __restrict__ means, float* __restrict__ out0)
{
    const int NQ = NN / 4;                       // 25000 float4 per (b,h)
    const int idx = blockIdx.x * 256 + threadIdx.x;   // 0 .. B*H*NQ-1
    const int q  = idx % NQ;
    const int bh = idx / NQ;                     // b*HORIZON + h
    const int b  = bh / HORIZON;
    const f32x4 v = *reinterpret_cast<const f32x4*>(
        means + (size_t)b * NN + 4 * q);
    *reinterpret_cast<f32x4*>(out0 + (size_t)idx * 4) = v;
}

// Region counts.
__global__ __launch_bounds__(256) void count_kernel(
    const int* __restrict__ cid, float* __restrict__ gcount)
{
    __shared__ float lc[NUM_REGIONS];
    const int tid = threadIdx.x;
    if (tid < NUM_REGIONS) lc[tid] = 0.0f;
    __syncthreads();
    const int n = blockIdx.x * 256 + tid;
    if (n < NN) atomicAdd(&lc[cid[n]], 1.0f);
    __syncthreads();
    if (tid < NUM_REGIONS) atomicAdd(&gcount[tid], lc[tid]);
}

// Regional means broadcast over horizon.
__global__ __launch_bounds__(256) void finalize_kernel(
    const float* __restrict__ gsum, const float* __restrict__ gcount,
    float* __restrict__ out1)
{
    const int idx = blockIdx.x * 256 + threadIdx.x;  // 0 .. B*R-1
    if (idx >= BB * NUM_REGIONS) return;
    const int b = idx >> 6;
    const int r = idx & 63;
    const float v = gsum[idx] / gcount[r];
    const size_t base = (size_t)b * HORIZON * NUM_REGIONS + r;
    #pragma unroll
    for (int h = 0; h < HORIZON; ++h) {
        out1[base + (size_t)h * NUM_REGIONS] = v;
    }
}

extern "C" void kernel_launch(void* const* d_in, const int* in_sizes, int n_in,
                              void* d_out, int out_size, void* d_ws, size_t ws_size,
                              hipStream_t stream) {
    const float* x   = (const float*)d_in[0];
    const int*   cid = (const int*)d_in[1];
    float* out0 = (float*)d_out;
    float* out1 = out0 + (size_t)BB * HORIZON * NN;

    float* means  = (float*)d_ws;                       // BB*NN floats (12.8 MB)
    float* gsum   = means + (size_t)BB * NN;            // BB*NUM_REGIONS floats
    float* gcount = gsum + BB * NUM_REGIONS;            // NUM_REGIONS floats

    (void)hipMemsetAsync(gsum, 0,
                   (BB * NUM_REGIONS + NUM_REGIONS) * sizeof(float), stream);

    count_kernel<<<(NN + 255) / 256, 256, 0, stream>>>(cid, gcount);

    dim3 gridR((NN / 2 + 255) / 256, BB);
    reduce_kernel<<<gridR, 256, 0, stream>>>(x, cid, means, gsum);

    const int nq4 = BB * HORIZON * (NN / 4);            // 8,000,000 (divisible by 256)
    broadcast_kernel<<<nq4 / 256, 256, 0, stream>>>(means, out0);

    finalize_kernel<<<(BB * NUM_REGIONS + 255) / 256, 256, 0, stream>>>(
        gsum, gcount, out1);
}